// Round 1
// baseline (1859.527 us; speedup 1.0000x reference)
//
#include <hip/hip_runtime.h>
#include <math.h>

#define NNODES 100000

// ---------------- degree / norm ----------------
__global__ void deg_kernel(const int* __restrict__ dst, int* __restrict__ deg, int E) {
    int e = blockIdx.x * blockDim.x + threadIdx.x;
    if (e < E) atomicAdd(&deg[dst[e]], 1);
}

__global__ void dinv_kernel(const int* __restrict__ deg, float* __restrict__ dinv, int n) {
    int i = blockIdx.x * blockDim.x + threadIdx.x;
    if (i < n) dinv[i] = 1.0f / sqrtf((float)(deg[i] + 1));   // +1: self-loop
}

// ---------------- exclusive scan (1 block, N=100k) ----------------
__global__ __launch_bounds__(1024) void scan_kernel(const int* __restrict__ deg,
                                                    int* __restrict__ off, int n) {
    __shared__ int part[1024];
    int t = threadIdx.x;
    int chunk = (n + 1023) >> 10;
    int lo = t * chunk;
    int hi = min(n, lo + chunk);
    int s = 0;
    for (int i = lo; i < hi; ++i) s += deg[i];
    part[t] = s;
    __syncthreads();
    if (t == 0) {
        int run = 0;
        for (int i = 0; i < 1024; ++i) { int v = part[i]; part[i] = run; run += v; }
        off[n] = run;   // == E
    }
    __syncthreads();
    int run = part[t];
    for (int i = lo; i < hi; ++i) { off[i] = run; run += deg[i]; }
}

// ---------------- CSR fill (counting sort by dst) ----------------
__global__ void fill_csr(const int* __restrict__ src, const int* __restrict__ dst,
                         const int* __restrict__ off, int* __restrict__ cur,
                         const float* __restrict__ dinv,
                         int* __restrict__ csr_s, float* __restrict__ csr_n, int E) {
    int e = blockIdx.x * blockDim.x + threadIdx.x;
    if (e >= E) return;
    int s = src[e], d = dst[e];
    int pos = off[d] + atomicAdd(&cur[d], 1);
    csr_s[pos] = s;
    csr_n[pos] = dinv[s] * dinv[d];
}

// ---------------- fp32 GEMM: [n,128] x [128,128] ----------------
__global__ __launch_bounds__(256) void gemm128(const float* __restrict__ A,
                                               const float* __restrict__ W,
                                               float* __restrict__ C, int n) {
    __shared__ float xs[64][33];     // +1 pad: break 4-way bank conflict on row reads
    __shared__ float ws[32][128];
    int t = threadIdx.x;
    int cg = t & 15;      // cols cg*8 .. cg*8+7
    int rg = t >> 4;      // rows rg*4 .. rg*4+3
    int row0 = blockIdx.x * 64;
    float acc[4][8];
#pragma unroll
    for (int i = 0; i < 4; ++i)
#pragma unroll
        for (int j = 0; j < 8; ++j) acc[i][j] = 0.f;

    for (int kt = 0; kt < 4; ++kt) {
        // stage x tile: 64 rows x 32 k
#pragma unroll
        for (int l = 0; l < 2; ++l) {
            int c = t + l * 256;            // 0..511
            int r = c >> 3;
            int k4 = (c & 7) * 4;
            int gr = row0 + r;
            float4 v = make_float4(0.f, 0.f, 0.f, 0.f);
            if (gr < n) v = *(const float4*)&A[(size_t)gr * 128 + kt * 32 + k4];
            xs[r][k4 + 0] = v.x; xs[r][k4 + 1] = v.y; xs[r][k4 + 2] = v.z; xs[r][k4 + 3] = v.w;
        }
        // stage W tile: 32 k x 128 cols
#pragma unroll
        for (int l = 0; l < 4; ++l) {
            int c = t + l * 256;            // 0..1023
            int kk = c >> 5;
            int c4 = (c & 31) * 4;
            *(float4*)&ws[kk][c4] = *(const float4*)&W[(size_t)(kt * 32 + kk) * 128 + c4];
        }
        __syncthreads();
#pragma unroll
        for (int kk = 0; kk < 32; ++kk) {
            float4 w0 = *(const float4*)&ws[kk][cg * 8];
            float4 w1 = *(const float4*)&ws[kk][cg * 8 + 4];
            float xv[4];
#pragma unroll
            for (int i = 0; i < 4; ++i) xv[i] = xs[rg * 4 + i][kk];
#pragma unroll
            for (int i = 0; i < 4; ++i) {
                acc[i][0] += xv[i] * w0.x; acc[i][1] += xv[i] * w0.y;
                acc[i][2] += xv[i] * w0.z; acc[i][3] += xv[i] * w0.w;
                acc[i][4] += xv[i] * w1.x; acc[i][5] += xv[i] * w1.y;
                acc[i][6] += xv[i] * w1.z; acc[i][7] += xv[i] * w1.w;
            }
        }
        __syncthreads();
    }
#pragma unroll
    for (int i = 0; i < 4; ++i) {
        int gr = row0 + rg * 4 + i;
        if (gr < n) {
#pragma unroll
            for (int j = 0; j < 8; j += 4) {
                float4 v = make_float4(acc[i][j], acc[i][j + 1], acc[i][j + 2], acc[i][j + 3]);
                *(float4*)&C[(size_t)gr * 128 + cg * 8 + j] = v;
            }
        }
    }
}

// ---------------- fp32 GEMM: [n,128] x [128,32] ----------------
__global__ __launch_bounds__(256) void gemm32(const float* __restrict__ A,
                                              const float* __restrict__ W,
                                              float* __restrict__ C, int n) {
    __shared__ float wsl[128 * 32];  // full W4, 16 KB
    __shared__ float xs[64][33];
    int t = threadIdx.x;
#pragma unroll
    for (int l = 0; l < 4; ++l) {
        int c = t + l * 256;          // 0..1023 float4 chunks
        *(float4*)&wsl[c * 4] = *(const float4*)&W[c * 4];
    }
    int row0 = blockIdx.x * 64;
    int c = t & 31;      // col
    int rg = t >> 5;     // rows rg*8 .. rg*8+7
    float acc[8];
#pragma unroll
    for (int j = 0; j < 8; ++j) acc[j] = 0.f;

    for (int kt = 0; kt < 4; ++kt) {
#pragma unroll
        for (int l = 0; l < 2; ++l) {
            int cc = t + l * 256;
            int r = cc >> 3;
            int k4 = (cc & 7) * 4;
            int gr = row0 + r;
            float4 v = make_float4(0.f, 0.f, 0.f, 0.f);
            if (gr < n) v = *(const float4*)&A[(size_t)gr * 128 + kt * 32 + k4];
            xs[r][k4 + 0] = v.x; xs[r][k4 + 1] = v.y; xs[r][k4 + 2] = v.z; xs[r][k4 + 3] = v.w;
        }
        __syncthreads();
#pragma unroll
        for (int kk = 0; kk < 32; ++kk) {
            float w = wsl[(kt * 32 + kk) * 32 + c];
#pragma unroll
            for (int j = 0; j < 8; ++j) acc[j] += xs[rg * 8 + j][kk] * w;
        }
        __syncthreads();
    }
#pragma unroll
    for (int j = 0; j < 8; ++j) {
        int gr = row0 + rg * 8 + j;
        if (gr < n) C[(size_t)gr * 32 + c] = acc[j];
    }
}

// ---------------- aggregation, F=128: one wave per node ----------------
__global__ __launch_bounds__(256) void agg128(const float* __restrict__ h,
                                              const int* __restrict__ off,
                                              const int* __restrict__ csr_s,
                                              const float* __restrict__ csr_n,
                                              const float* __restrict__ dinv,
                                              const float* __restrict__ bias,
                                              float* __restrict__ out, int n, int do_relu) {
    int wid = (blockIdx.x * blockDim.x + threadIdx.x) >> 6;
    if (wid >= n) return;
    int lane = threadIdx.x & 63;
    float dl = dinv[wid];
    float sl = dl * dl;
    float a0 = h[(size_t)wid * 128 + lane] * sl;          // self-loop
    float a1 = h[(size_t)wid * 128 + 64 + lane] * sl;
    int i0 = off[wid], i1 = off[wid + 1];
    for (int i = i0; i < i1; ++i) {
        int s = csr_s[i];
        float w = csr_n[i];
        a0 += h[(size_t)s * 128 + lane] * w;
        a1 += h[(size_t)s * 128 + 64 + lane] * w;
    }
    a0 += bias[lane];
    a1 += bias[64 + lane];
    if (do_relu) { a0 = fmaxf(a0, 0.f); a1 = fmaxf(a1, 0.f); }
    out[(size_t)wid * 128 + lane] = a0;
    out[(size_t)wid * 128 + 64 + lane] = a1;
}

// ---------------- aggregation F=32 + log_softmax ----------------
__global__ __launch_bounds__(256) void agg32_lsm(const float* __restrict__ h,
                                                 const int* __restrict__ off,
                                                 const int* __restrict__ csr_s,
                                                 const float* __restrict__ csr_n,
                                                 const float* __restrict__ dinv,
                                                 const float* __restrict__ bias,
                                                 float* __restrict__ out, int n) {
    int idx = blockIdx.x * blockDim.x + threadIdx.x;
    int node = idx >> 5;
    if (node >= n) return;
    int lane = idx & 31;
    float dl = dinv[node];
    float a = h[(size_t)node * 32 + lane] * dl * dl;
    int i0 = off[node], i1 = off[node + 1];
    for (int i = i0; i < i1; ++i)
        a += h[(size_t)csr_s[i] * 32 + lane] * csr_n[i];
    a += bias[lane];
    // log_softmax over the 32 lanes of this half-wave
    float m = a;
    for (int d = 16; d; d >>= 1) m = fmaxf(m, __shfl_xor(m, d, 32));
    float e = expf(a - m);
    float ssum = e;
    for (int d = 16; d; d >>= 1) ssum += __shfl_xor(ssum, d, 32);
    out[(size_t)node * 32 + lane] = a - m - logf(ssum);
}

extern "C" void kernel_launch(void* const* d_in, const int* in_sizes, int n_in,
                              void* d_out, int out_size, void* d_ws, size_t ws_size,
                              hipStream_t stream) {
    const float* x  = (const float*)d_in[0];
    const int*   ei = (const int*)d_in[1];
    const float* W1 = (const float*)d_in[2];
    const float* b1 = (const float*)d_in[3];
    const float* W2 = (const float*)d_in[4];
    const float* b2 = (const float*)d_in[5];
    const float* W3 = (const float*)d_in[6];
    const float* b3 = (const float*)d_in[7];
    const float* W4 = (const float*)d_in[8];
    const float* b4 = (const float*)d_in[9];
    float* out = (float*)d_out;

    const int N = NNODES;
    const int E = in_sizes[1] / 2;

    char* ws = (char*)d_ws;
    size_t o = 0;
    auto alloc = [&](size_t bytes) -> void* {
        void* p = ws + o;
        o += (bytes + 255) & ~(size_t)255;
        return p;
    };
    int*   deg   = (int*)alloc((size_t)N * 4);
    int*   cur   = (int*)alloc((size_t)N * 4);
    int*   off   = (int*)alloc((size_t)(N + 1) * 4);
    float* dinv  = (float*)alloc((size_t)N * 4);
    int*   csr_s = (int*)alloc((size_t)E * 4);
    float* csr_n = (float*)alloc((size_t)E * 4);
    float* hbuf  = (float*)alloc((size_t)N * 128 * 4);
    float* gbuf  = (float*)alloc((size_t)N * 128 * 4);

    const int* srcv = ei;
    const int* dstv = ei + E;

    hipMemsetAsync(deg, 0, (size_t)N * 4, stream);
    hipMemsetAsync(cur, 0, (size_t)N * 4, stream);

    deg_kernel<<<(E + 255) / 256, 256, 0, stream>>>(dstv, deg, E);
    dinv_kernel<<<(N + 255) / 256, 256, 0, stream>>>(deg, dinv, N);
    scan_kernel<<<1, 1024, 0, stream>>>(deg, off, N);
    fill_csr<<<(E + 255) / 256, 256, 0, stream>>>(srcv, dstv, off, cur, dinv, csr_s, csr_n, E);

    int gemm_blocks = (N + 63) / 64;
    int agg128_blocks = (N + 3) / 4;      // 4 waves (nodes) per 256-thread block
    int agg32_blocks = (N * 32 + 255) / 256;

    // Layer 1
    gemm128<<<gemm_blocks, 256, 0, stream>>>(x, W1, hbuf, N);
    agg128<<<agg128_blocks, 256, 0, stream>>>(hbuf, off, csr_s, csr_n, dinv, b1, gbuf, N, 1);
    // Layer 2
    gemm128<<<gemm_blocks, 256, 0, stream>>>(gbuf, W2, hbuf, N);
    agg128<<<agg128_blocks, 256, 0, stream>>>(hbuf, off, csr_s, csr_n, dinv, b2, gbuf, N, 1);
    // Layer 3
    gemm128<<<gemm_blocks, 256, 0, stream>>>(gbuf, W3, hbuf, N);
    agg128<<<agg128_blocks, 256, 0, stream>>>(hbuf, off, csr_s, csr_n, dinv, b3, gbuf, N, 1);
    // Layer 4: GEMM to 32 cols first (4x less gather traffic), then agg + log_softmax
    gemm32<<<gemm_blocks, 256, 0, stream>>>(gbuf, W4, hbuf, N);
    agg32_lsm<<<agg32_blocks, 256, 0, stream>>>(hbuf, off, csr_s, csr_n, dinv, b4, out, N);
}

// Round 2
// 1217.155 us; speedup vs baseline: 1.5278x; 1.5278x over previous
//
#include <hip/hip_runtime.h>
#include <hip/hip_bf16.h>
#include <math.h>

#define NNODES 100000

typedef __hip_bfloat16 bf16;

__device__ inline unsigned pack_bf16x2(float a, float b) {
    __hip_bfloat162 p;
    p.x = __float2bfloat16(a);
    p.y = __float2bfloat16(b);
    return *(unsigned*)&p;
}

__device__ inline float2 unpack_bf16x2(unsigned u) {
    __hip_bfloat162 p = *(__hip_bfloat162*)&u;
    return make_float2(__bfloat162float(p.x), __bfloat162float(p.y));
}

// ---------------- degree / norm ----------------
__global__ void deg_kernel(const int* __restrict__ dst, int* __restrict__ deg, int E) {
    int e = blockIdx.x * blockDim.x + threadIdx.x;
    if (e < E) atomicAdd(&deg[dst[e]], 1);
}

__global__ void dinv_kernel(const int* __restrict__ deg, float* __restrict__ dinv, int n) {
    int i = blockIdx.x * blockDim.x + threadIdx.x;
    if (i < n) dinv[i] = 1.0f / sqrtf((float)(deg[i] + 1));   // +1: self-loop
}

// ---------------- exclusive scan (1 block, N=100k) ----------------
__global__ __launch_bounds__(1024) void scan_kernel(const int* __restrict__ deg,
                                                    int* __restrict__ off, int n) {
    __shared__ int part[1024];
    int t = threadIdx.x;
    int chunk = (n + 1023) >> 10;
    int lo = t * chunk;
    int hi = min(n, lo + chunk);
    int s = 0;
    for (int i = lo; i < hi; ++i) s += deg[i];
    part[t] = s;
    __syncthreads();
    if (t == 0) {
        int run = 0;
        for (int i = 0; i < 1024; ++i) { int v = part[i]; part[i] = run; run += v; }
        off[n] = run;   // == E
    }
    __syncthreads();
    int run = part[t];
    for (int i = lo; i < hi; ++i) { off[i] = run; run += deg[i]; }
}

// ---------------- CSR fill (counting sort by dst) ----------------
__global__ void fill_csr(const int* __restrict__ src, const int* __restrict__ dst,
                         const int* __restrict__ off, int* __restrict__ cur,
                         const float* __restrict__ dinv,
                         int* __restrict__ csr_s, float* __restrict__ csr_n, int E) {
    int e = blockIdx.x * blockDim.x + threadIdx.x;
    if (e >= E) return;
    int s = src[e], d = dst[e];
    int pos = off[d] + atomicAdd(&cur[d], 1);
    csr_s[pos] = s;
    csr_n[pos] = dinv[s] * dinv[d];
}

// ---------------- fp32 GEMM: [n,128] x [128,128] -> bf16 ----------------
__global__ __launch_bounds__(256) void gemm128(const float* __restrict__ A,
                                               const float* __restrict__ W,
                                               bf16* __restrict__ C, int n) {
    __shared__ float xs[64][33];     // +1 pad: break bank conflicts on row reads
    __shared__ float ws[32][128];
    int t = threadIdx.x;
    int cg = t & 15;      // cols cg*8 .. cg*8+7
    int rg = t >> 4;      // rows rg*4 .. rg*4+3
    int row0 = blockIdx.x * 64;
    float acc[4][8];
#pragma unroll
    for (int i = 0; i < 4; ++i)
#pragma unroll
        for (int j = 0; j < 8; ++j) acc[i][j] = 0.f;

    for (int kt = 0; kt < 4; ++kt) {
#pragma unroll
        for (int l = 0; l < 2; ++l) {
            int c = t + l * 256;            // 0..511
            int r = c >> 3;
            int k4 = (c & 7) * 4;
            int gr = row0 + r;
            float4 v = make_float4(0.f, 0.f, 0.f, 0.f);
            if (gr < n) v = *(const float4*)&A[(size_t)gr * 128 + kt * 32 + k4];
            xs[r][k4 + 0] = v.x; xs[r][k4 + 1] = v.y; xs[r][k4 + 2] = v.z; xs[r][k4 + 3] = v.w;
        }
#pragma unroll
        for (int l = 0; l < 4; ++l) {
            int c = t + l * 256;            // 0..1023
            int kk = c >> 5;
            int c4 = (c & 31) * 4;
            *(float4*)&ws[kk][c4] = *(const float4*)&W[(size_t)(kt * 32 + kk) * 128 + c4];
        }
        __syncthreads();
#pragma unroll
        for (int kk = 0; kk < 32; ++kk) {
            float4 w0 = *(const float4*)&ws[kk][cg * 8];
            float4 w1 = *(const float4*)&ws[kk][cg * 8 + 4];
            float xv[4];
#pragma unroll
            for (int i = 0; i < 4; ++i) xv[i] = xs[rg * 4 + i][kk];
#pragma unroll
            for (int i = 0; i < 4; ++i) {
                acc[i][0] += xv[i] * w0.x; acc[i][1] += xv[i] * w0.y;
                acc[i][2] += xv[i] * w0.z; acc[i][3] += xv[i] * w0.w;
                acc[i][4] += xv[i] * w1.x; acc[i][5] += xv[i] * w1.y;
                acc[i][6] += xv[i] * w1.z; acc[i][7] += xv[i] * w1.w;
            }
        }
        __syncthreads();
    }
#pragma unroll
    for (int i = 0; i < 4; ++i) {
        int gr = row0 + rg * 4 + i;
        if (gr < n) {
            uint4 u;
            u.x = pack_bf16x2(acc[i][0], acc[i][1]);
            u.y = pack_bf16x2(acc[i][2], acc[i][3]);
            u.z = pack_bf16x2(acc[i][4], acc[i][5]);
            u.w = pack_bf16x2(acc[i][6], acc[i][7]);
            *(uint4*)&C[(size_t)gr * 128 + cg * 8] = u;   // 16B aligned (cg*8 bf16)
        }
    }
}

// ---------------- fp32 GEMM: [n,128] x [128,32] -> bf16 ----------------
__global__ __launch_bounds__(256) void gemm32(const float* __restrict__ A,
                                              const float* __restrict__ W,
                                              bf16* __restrict__ C, int n) {
    __shared__ float wsl[128 * 32];  // full W4, 16 KB
    __shared__ float xs[64][33];
    int t = threadIdx.x;
#pragma unroll
    for (int l = 0; l < 4; ++l) {
        int c = t + l * 256;          // 0..1023 float4 chunks
        *(float4*)&wsl[c * 4] = *(const float4*)&W[c * 4];
    }
    int row0 = blockIdx.x * 64;
    int c = t & 31;      // col
    int rg = t >> 5;     // rows rg*8 .. rg*8+7
    float acc[8];
#pragma unroll
    for (int j = 0; j < 8; ++j) acc[j] = 0.f;

    for (int kt = 0; kt < 4; ++kt) {
#pragma unroll
        for (int l = 0; l < 2; ++l) {
            int cc = t + l * 256;
            int r = cc >> 3;
            int k4 = (cc & 7) * 4;
            int gr = row0 + r;
            float4 v = make_float4(0.f, 0.f, 0.f, 0.f);
            if (gr < n) v = *(const float4*)&A[(size_t)gr * 128 + kt * 32 + k4];
            xs[r][k4 + 0] = v.x; xs[r][k4 + 1] = v.y; xs[r][k4 + 2] = v.z; xs[r][k4 + 3] = v.w;
        }
        __syncthreads();
#pragma unroll
        for (int kk = 0; kk < 32; ++kk) {
            float w = wsl[(kt * 32 + kk) * 32 + c];
#pragma unroll
            for (int j = 0; j < 8; ++j) acc[j] += xs[rg * 8 + j][kk] * w;
        }
        __syncthreads();
    }
#pragma unroll
    for (int j = 0; j < 8; ++j) {
        int gr = row0 + rg * 8 + j;
        if (gr < n) C[(size_t)gr * 32 + c] = __float2bfloat16(acc[j]);
    }
}

// ---------------- aggregation, F=128 bf16 gather: one wave per node ----------------
__global__ __launch_bounds__(256) void agg128(const bf16* __restrict__ h,
                                              const int* __restrict__ off,
                                              const int* __restrict__ csr_s,
                                              const float* __restrict__ csr_n,
                                              const float* __restrict__ dinv,
                                              const float* __restrict__ bias,
                                              float* __restrict__ out, int n, int do_relu) {
    int wid = (blockIdx.x * blockDim.x + threadIdx.x) >> 6;
    if (wid >= n) return;
    int lane = threadIdx.x & 63;
    const unsigned* h32 = (const unsigned*)h;     // row = 64 dwords (128 bf16)
    float dl = dinv[wid];
    float sl = dl * dl;
    float2 f = unpack_bf16x2(h32[(size_t)wid * 64 + lane]);   // self-loop
    float a0 = f.x * sl, a1 = f.y * sl;
    int i0 = off[wid], i1 = off[wid + 1];
    int i = i0;
    for (; i + 4 <= i1; i += 4) {
        int s0 = csr_s[i], s1 = csr_s[i + 1], s2 = csr_s[i + 2], s3 = csr_s[i + 3];
        float w0 = csr_n[i], w1 = csr_n[i + 1], w2 = csr_n[i + 2], w3 = csr_n[i + 3];
        unsigned u0 = h32[(size_t)s0 * 64 + lane];
        unsigned u1 = h32[(size_t)s1 * 64 + lane];
        unsigned u2 = h32[(size_t)s2 * 64 + lane];
        unsigned u3 = h32[(size_t)s3 * 64 + lane];
        float2 f0 = unpack_bf16x2(u0), f1 = unpack_bf16x2(u1);
        float2 f2 = unpack_bf16x2(u2), f3 = unpack_bf16x2(u3);
        a0 += f0.x * w0; a1 += f0.y * w0;
        a0 += f1.x * w1; a1 += f1.y * w1;
        a0 += f2.x * w2; a1 += f2.y * w2;
        a0 += f3.x * w3; a1 += f3.y * w3;
    }
    for (; i < i1; ++i) {
        int s = csr_s[i];
        float w = csr_n[i];
        float2 fv = unpack_bf16x2(h32[(size_t)s * 64 + lane]);
        a0 += fv.x * w; a1 += fv.y * w;
    }
    float2 bv = *(const float2*)&bias[lane * 2];
    a0 += bv.x; a1 += bv.y;
    if (do_relu) { a0 = fmaxf(a0, 0.f); a1 = fmaxf(a1, 0.f); }
    *(float2*)&out[(size_t)wid * 128 + lane * 2] = make_float2(a0, a1);
}

// ---------------- aggregation F=32 bf16 gather + log_softmax ----------------
__global__ __launch_bounds__(256) void agg32_lsm(const bf16* __restrict__ h,
                                                 const int* __restrict__ off,
                                                 const int* __restrict__ csr_s,
                                                 const float* __restrict__ csr_n,
                                                 const float* __restrict__ dinv,
                                                 const float* __restrict__ bias,
                                                 float* __restrict__ out, int n) {
    int idx = blockIdx.x * blockDim.x + threadIdx.x;
    int node = idx >> 5;
    if (node >= n) return;
    int lane = idx & 31;
    float dl = dinv[node];
    float a = __bfloat162float(h[(size_t)node * 32 + lane]) * dl * dl;
    int i0 = off[node], i1 = off[node + 1];
    int i = i0;
    for (; i + 4 <= i1; i += 4) {
        int s0 = csr_s[i], s1 = csr_s[i + 1], s2 = csr_s[i + 2], s3 = csr_s[i + 3];
        float w0 = csr_n[i], w1 = csr_n[i + 1], w2 = csr_n[i + 2], w3 = csr_n[i + 3];
        float v0 = __bfloat162float(h[(size_t)s0 * 32 + lane]);
        float v1 = __bfloat162float(h[(size_t)s1 * 32 + lane]);
        float v2 = __bfloat162float(h[(size_t)s2 * 32 + lane]);
        float v3 = __bfloat162float(h[(size_t)s3 * 32 + lane]);
        a += v0 * w0 + v1 * w1 + v2 * w2 + v3 * w3;
    }
    for (; i < i1; ++i)
        a += __bfloat162float(h[(size_t)csr_s[i] * 32 + lane]) * csr_n[i];
    a += bias[lane];
    // log_softmax over the 32 lanes of this half-wave
    float m = a;
    for (int d = 16; d; d >>= 1) m = fmaxf(m, __shfl_xor(m, d, 32));
    float e = expf(a - m);
    float ssum = e;
    for (int d = 16; d; d >>= 1) ssum += __shfl_xor(ssum, d, 32);
    out[(size_t)node * 32 + lane] = a - m - logf(ssum);
}

extern "C" void kernel_launch(void* const* d_in, const int* in_sizes, int n_in,
                              void* d_out, int out_size, void* d_ws, size_t ws_size,
                              hipStream_t stream) {
    const float* x  = (const float*)d_in[0];
    const int*   ei = (const int*)d_in[1];
    const float* W1 = (const float*)d_in[2];
    const float* b1 = (const float*)d_in[3];
    const float* W2 = (const float*)d_in[4];
    const float* b2 = (const float*)d_in[5];
    const float* W3 = (const float*)d_in[6];
    const float* b3 = (const float*)d_in[7];
    const float* W4 = (const float*)d_in[8];
    const float* b4 = (const float*)d_in[9];
    float* out = (float*)d_out;

    const int N = NNODES;
    const int E = in_sizes[1] / 2;

    char* ws = (char*)d_ws;
    size_t o = 0;
    auto alloc = [&](size_t bytes) -> void* {
        void* p = ws + o;
        o += (bytes + 255) & ~(size_t)255;
        return p;
    };
    int*   deg   = (int*)alloc((size_t)N * 4);
    int*   cur   = (int*)alloc((size_t)N * 4);
    int*   off   = (int*)alloc((size_t)(N + 1) * 4);
    float* dinv  = (float*)alloc((size_t)N * 4);
    int*   csr_s = (int*)alloc((size_t)E * 4);
    float* csr_n = (float*)alloc((size_t)E * 4);
    bf16*  hbuf  = (bf16*)alloc((size_t)N * 128 * 2);
    float* gbuf  = (float*)alloc((size_t)N * 128 * 4);

    const int* srcv = ei;
    const int* dstv = ei + E;

    hipMemsetAsync(deg, 0, (size_t)N * 4, stream);
    hipMemsetAsync(cur, 0, (size_t)N * 4, stream);

    deg_kernel<<<(E + 255) / 256, 256, 0, stream>>>(dstv, deg, E);
    dinv_kernel<<<(N + 255) / 256, 256, 0, stream>>>(deg, dinv, N);
    scan_kernel<<<1, 1024, 0, stream>>>(deg, off, N);
    fill_csr<<<(E + 255) / 256, 256, 0, stream>>>(srcv, dstv, off, cur, dinv, csr_s, csr_n, E);

    int gemm_blocks = (N + 63) / 64;
    int agg128_blocks = (N + 3) / 4;      // 4 waves (nodes) per 256-thread block
    int agg32_blocks = (N * 32 + 255) / 256;

    // Layer 1
    gemm128<<<gemm_blocks, 256, 0, stream>>>(x, W1, hbuf, N);
    agg128<<<agg128_blocks, 256, 0, stream>>>(hbuf, off, csr_s, csr_n, dinv, b1, gbuf, N, 1);
    // Layer 2
    gemm128<<<gemm_blocks, 256, 0, stream>>>(gbuf, W2, hbuf, N);
    agg128<<<agg128_blocks, 256, 0, stream>>>(hbuf, off, csr_s, csr_n, dinv, b2, gbuf, N, 1);
    // Layer 3
    gemm128<<<gemm_blocks, 256, 0, stream>>>(gbuf, W3, hbuf, N);
    agg128<<<agg128_blocks, 256, 0, stream>>>(hbuf, off, csr_s, csr_n, dinv, b3, gbuf, N, 1);
    // Layer 4: GEMM to 32 cols first (4x less gather traffic), then agg + log_softmax
    gemm32<<<gemm_blocks, 256, 0, stream>>>(gbuf, W4, hbuf, N);
    agg32_lsm<<<agg32_blocks, 256, 0, stream>>>(hbuf, off, csr_s, csr_n, dinv, b4, out, N);
}

// Round 3
// 1072.072 us; speedup vs baseline: 1.7345x; 1.1353x over previous
//
#include <hip/hip_runtime.h>
#include <hip/hip_bf16.h>
#include <math.h>

#define NNODES 100000

typedef __hip_bfloat16 bf16;
typedef __attribute__((ext_vector_type(8))) short short8;   // bf16x8 MFMA A/B frag (4 VGPRs)
typedef __attribute__((ext_vector_type(4))) float f32x4;    // MFMA C/D frag

__device__ inline unsigned pack_bf16x2(float a, float b) {
    __hip_bfloat162 p;
    p.x = __float2bfloat16(a);
    p.y = __float2bfloat16(b);
    return *(unsigned*)&p;
}

__device__ inline float2 unpack_bf16x2(unsigned u) {
    __hip_bfloat162 p = *(__hip_bfloat162*)&u;
    return make_float2(__bfloat162float(p.x), __bfloat162float(p.y));
}

// ---------------- degree / norm ----------------
__global__ void deg_kernel(const int* __restrict__ dst, int* __restrict__ deg, int E) {
    int e = blockIdx.x * blockDim.x + threadIdx.x;
    if (e < E) atomicAdd(&deg[dst[e]], 1);
}

__global__ void dinv_kernel(const int* __restrict__ deg, float* __restrict__ dinv, int n) {
    int i = blockIdx.x * blockDim.x + threadIdx.x;
    if (i < n) dinv[i] = 1.0f / sqrtf((float)(deg[i] + 1));   // +1: self-loop
}

// ---------------- exclusive scan (1 block, N=100k) ----------------
__global__ __launch_bounds__(1024) void scan_kernel(const int* __restrict__ deg,
                                                    int* __restrict__ off, int n) {
    __shared__ int part[1024];
    int t = threadIdx.x;
    int chunk = (n + 1023) >> 10;
    int lo = t * chunk;
    int hi = min(n, lo + chunk);
    int s = 0;
    for (int i = lo; i < hi; ++i) s += deg[i];
    part[t] = s;
    __syncthreads();
    if (t == 0) {
        int run = 0;
        for (int i = 0; i < 1024; ++i) { int v = part[i]; part[i] = run; run += v; }
        off[n] = run;   // == E
    }
    __syncthreads();
    int run = part[t];
    for (int i = lo; i < hi; ++i) { off[i] = run; run += deg[i]; }
}

// ---------------- CSR fill: ONE 8B packed scatter per edge ----------------
__global__ void fill_csr(const int* __restrict__ src, const int* __restrict__ dst,
                         const int* __restrict__ off, int* __restrict__ cur,
                         const float* __restrict__ dinv,
                         int2* __restrict__ edges, int E) {
    int e = blockIdx.x * blockDim.x + threadIdx.x;
    if (e >= E) return;
    int s = src[e], d = dst[e];
    int pos = off[d] + atomicAdd(&cur[d], 1);
    float w = dinv[s] * dinv[d];
    edges[pos] = make_int2(s, __float_as_int(w));
}

// ---------------- weight prep: WT[n][k] = bf16(W[k][n]) ----------------
__global__ void prep_w(const float* __restrict__ W, bf16* __restrict__ WT, int K, int Nout) {
    int idx = blockIdx.x * blockDim.x + threadIdx.x;
    if (idx >= K * Nout) return;
    int nn = idx / K;
    int kk = idx - nn * K;
    WT[idx] = __float2bfloat16(W[kk * Nout + nn]);
}

// ---------------- MFMA GEMM, A fp32 [n,128] x WT bf16 [128][128] -> bf16 ----------------
// wave = 16 rows x 128 cols (8 16x16 tiles); no LDS, WT stays hot in L1/L2.
__global__ __launch_bounds__(256) void gemm128_f32A(const float* __restrict__ A,
                                                    const bf16* __restrict__ WT,
                                                    bf16* __restrict__ C, int n) {
    int wave = threadIdx.x >> 6;
    int lane = threadIdx.x & 63;
    int m = lane & 15;          // A row within tile / C col
    int q = lane >> 4;          // quad: k-group for A/B, row-group for C
    int row_base = blockIdx.x * 64 + wave * 16;
    int arow = min(row_base + m, n - 1);

    f32x4 acc[8];
#pragma unroll
    for (int c = 0; c < 8; ++c) acc[c] = (f32x4)(0.f);

#pragma unroll
    for (int kt = 0; kt < 4; ++kt) {
        const float* ap = &A[(size_t)arow * 128 + kt * 32 + q * 8];
        float4 f0 = *(const float4*)ap;
        float4 f1 = *(const float4*)(ap + 4);
        union { uint4 u; short8 s; } cv;
        cv.u.x = pack_bf16x2(f0.x, f0.y);
        cv.u.y = pack_bf16x2(f0.z, f0.w);
        cv.u.z = pack_bf16x2(f1.x, f1.y);
        cv.u.w = pack_bf16x2(f1.z, f1.w);
        short8 af = cv.s;
#pragma unroll
        for (int c = 0; c < 8; ++c) {
            short8 bf = *(const short8*)&WT[(size_t)(c * 16 + m) * 128 + kt * 32 + q * 8];
            acc[c] = __builtin_amdgcn_mfma_f32_16x16x32_bf16(af, bf, acc[c], 0, 0, 0);
        }
    }
#pragma unroll
    for (int c = 0; c < 8; ++c) {
#pragma unroll
        for (int r = 0; r < 4; ++r) {
            int row = row_base + q * 4 + r;
            if (row < n) C[(size_t)row * 128 + c * 16 + m] = __float2bfloat16(acc[c][r]);
        }
    }
}

// ---------------- MFMA GEMM, A bf16 [n,128] x WT bf16 [128][128] -> bf16 ----------------
__global__ __launch_bounds__(256) void gemm128_bf16A(const bf16* __restrict__ A,
                                                     const bf16* __restrict__ WT,
                                                     bf16* __restrict__ C, int n) {
    int wave = threadIdx.x >> 6;
    int lane = threadIdx.x & 63;
    int m = lane & 15;
    int q = lane >> 4;
    int row_base = blockIdx.x * 64 + wave * 16;
    int arow = min(row_base + m, n - 1);

    f32x4 acc[8];
#pragma unroll
    for (int c = 0; c < 8; ++c) acc[c] = (f32x4)(0.f);

#pragma unroll
    for (int kt = 0; kt < 4; ++kt) {
        short8 af = *(const short8*)&A[(size_t)arow * 128 + kt * 32 + q * 8];
#pragma unroll
        for (int c = 0; c < 8; ++c) {
            short8 bf = *(const short8*)&WT[(size_t)(c * 16 + m) * 128 + kt * 32 + q * 8];
            acc[c] = __builtin_amdgcn_mfma_f32_16x16x32_bf16(af, bf, acc[c], 0, 0, 0);
        }
    }
#pragma unroll
    for (int c = 0; c < 8; ++c) {
#pragma unroll
        for (int r = 0; r < 4; ++r) {
            int row = row_base + q * 4 + r;
            if (row < n) C[(size_t)row * 128 + c * 16 + m] = __float2bfloat16(acc[c][r]);
        }
    }
}

// ---------------- MFMA GEMM, A bf16 [n,128] x WT4 bf16 [32][128] -> bf16 [n,32] ----------------
__global__ __launch_bounds__(256) void gemm32_bf16A(const bf16* __restrict__ A,
                                                    const bf16* __restrict__ WT,
                                                    bf16* __restrict__ C, int n) {
    int wave = threadIdx.x >> 6;
    int lane = threadIdx.x & 63;
    int m = lane & 15;
    int q = lane >> 4;
    int row_base = blockIdx.x * 64 + wave * 16;
    int arow = min(row_base + m, n - 1);

    f32x4 acc[2];
    acc[0] = (f32x4)(0.f);
    acc[1] = (f32x4)(0.f);

#pragma unroll
    for (int kt = 0; kt < 4; ++kt) {
        short8 af = *(const short8*)&A[(size_t)arow * 128 + kt * 32 + q * 8];
#pragma unroll
        for (int c = 0; c < 2; ++c) {
            short8 bf = *(const short8*)&WT[(size_t)(c * 16 + m) * 128 + kt * 32 + q * 8];
            acc[c] = __builtin_amdgcn_mfma_f32_16x16x32_bf16(af, bf, acc[c], 0, 0, 0);
        }
    }
#pragma unroll
    for (int c = 0; c < 2; ++c) {
#pragma unroll
        for (int r = 0; r < 4; ++r) {
            int row = row_base + q * 4 + r;
            if (row < n) C[(size_t)row * 32 + c * 16 + m] = __float2bfloat16(acc[c][r]);
        }
    }
}

// ---------------- aggregation, F=128 bf16 gather -> bf16 out (one wave/node) ----------------
__global__ __launch_bounds__(256) void agg128(const bf16* __restrict__ h,
                                              const int* __restrict__ off,
                                              const int2* __restrict__ edges,
                                              const float* __restrict__ dinv,
                                              const float* __restrict__ bias,
                                              bf16* __restrict__ out, int n) {
    int wid = (blockIdx.x * blockDim.x + threadIdx.x) >> 6;
    if (wid >= n) return;
    int lane = threadIdx.x & 63;
    const unsigned* h32 = (const unsigned*)h;     // row = 64 dwords (128 bf16)
    float dl = dinv[wid];
    float sl = dl * dl;
    float2 f = unpack_bf16x2(h32[(size_t)wid * 64 + lane]);   // self-loop
    float a0 = f.x * sl, a1 = f.y * sl;
    int i0 = off[wid], i1 = off[wid + 1];
    int i = i0;
    for (; i + 8 <= i1; i += 8) {
        int2 ee[8];
#pragma unroll
        for (int j = 0; j < 8; ++j) ee[j] = edges[i + j];
        unsigned uu[8];
#pragma unroll
        for (int j = 0; j < 8; ++j) uu[j] = h32[(size_t)ee[j].x * 64 + lane];
#pragma unroll
        for (int j = 0; j < 8; ++j) {
            float w = __int_as_float(ee[j].y);
            float2 fv = unpack_bf16x2(uu[j]);
            a0 += fv.x * w; a1 += fv.y * w;
        }
    }
    for (; i < i1; ++i) {
        int2 e = edges[i];
        float w = __int_as_float(e.y);
        float2 fv = unpack_bf16x2(h32[(size_t)e.x * 64 + lane]);
        a0 += fv.x * w; a1 += fv.y * w;
    }
    float2 bv = *(const float2*)&bias[lane * 2];
    a0 += bv.x; a1 += bv.y;
    a0 = fmaxf(a0, 0.f); a1 = fmaxf(a1, 0.f);     // ReLU (layers 1-3 only)
    ((unsigned*)out)[(size_t)wid * 64 + lane] = pack_bf16x2(a0, a1);
}

// ---------------- aggregation F=32 bf16 gather + log_softmax -> fp32 ----------------
__global__ __launch_bounds__(256) void agg32_lsm(const bf16* __restrict__ h,
                                                 const int* __restrict__ off,
                                                 const int2* __restrict__ edges,
                                                 const float* __restrict__ dinv,
                                                 const float* __restrict__ bias,
                                                 float* __restrict__ out, int n) {
    int idx = blockIdx.x * blockDim.x + threadIdx.x;
    int node = idx >> 5;
    if (node >= n) return;
    int lane = idx & 31;
    const unsigned short* hu = (const unsigned short*)h;
    float dl = dinv[node];
    float a = __bfloat162float(h[(size_t)node * 32 + lane]) * dl * dl;
    int i0 = off[node], i1 = off[node + 1];
    int i = i0;
    for (; i + 8 <= i1; i += 8) {
        int2 ee[8];
#pragma unroll
        for (int j = 0; j < 8; ++j) ee[j] = edges[i + j];
        unsigned short vv[8];
#pragma unroll
        for (int j = 0; j < 8; ++j) vv[j] = hu[(size_t)ee[j].x * 32 + lane];
#pragma unroll
        for (int j = 0; j < 8; ++j) {
            bf16 b = *(bf16*)&vv[j];
            a += __bfloat162float(b) * __int_as_float(ee[j].y);
        }
    }
    for (; i < i1; ++i) {
        int2 e = edges[i];
        a += __bfloat162float(h[(size_t)e.x * 32 + lane]) * __int_as_float(e.y);
    }
    a += bias[lane];
    float mx = a;
    for (int d = 16; d; d >>= 1) mx = fmaxf(mx, __shfl_xor(mx, d, 32));
    float e = expf(a - mx);
    float ssum = e;
    for (int d = 16; d; d >>= 1) ssum += __shfl_xor(ssum, d, 32);
    out[(size_t)node * 32 + lane] = a - mx - logf(ssum);
}

extern "C" void kernel_launch(void* const* d_in, const int* in_sizes, int n_in,
                              void* d_out, int out_size, void* d_ws, size_t ws_size,
                              hipStream_t stream) {
    const float* x  = (const float*)d_in[0];
    const int*   ei = (const int*)d_in[1];
    const float* W1 = (const float*)d_in[2];
    const float* b1 = (const float*)d_in[3];
    const float* W2 = (const float*)d_in[4];
    const float* b2 = (const float*)d_in[5];
    const float* W3 = (const float*)d_in[6];
    const float* b3 = (const float*)d_in[7];
    const float* W4 = (const float*)d_in[8];
    const float* b4 = (const float*)d_in[9];
    float* out = (float*)d_out;

    const int N = NNODES;
    const int E = in_sizes[1] / 2;

    char* ws = (char*)d_ws;
    size_t o = 0;
    auto alloc = [&](size_t bytes) -> void* {
        void* p = ws + o;
        o += (bytes + 255) & ~(size_t)255;
        return p;
    };
    int*   deg   = (int*)alloc((size_t)N * 4);
    int*   cur   = (int*)alloc((size_t)N * 4);
    int*   off   = (int*)alloc((size_t)(N + 1) * 4);
    float* dinv  = (float*)alloc((size_t)N * 4);
    int2*  edges = (int2*)alloc((size_t)E * 8);
    bf16*  wt1   = (bf16*)alloc((size_t)128 * 128 * 2);
    bf16*  wt2   = (bf16*)alloc((size_t)128 * 128 * 2);
    bf16*  wt3   = (bf16*)alloc((size_t)128 * 128 * 2);
    bf16*  wt4   = (bf16*)alloc((size_t)32 * 128 * 2);
    bf16*  hbuf  = (bf16*)alloc((size_t)N * 128 * 2);
    bf16*  gbuf  = (bf16*)alloc((size_t)N * 128 * 2);

    const int* srcv = ei;
    const int* dstv = ei + E;

    hipMemsetAsync(deg, 0, (size_t)N * 4, stream);
    hipMemsetAsync(cur, 0, (size_t)N * 4, stream);

    deg_kernel<<<(E + 255) / 256, 256, 0, stream>>>(dstv, deg, E);
    dinv_kernel<<<(N + 255) / 256, 256, 0, stream>>>(deg, dinv, N);
    scan_kernel<<<1, 1024, 0, stream>>>(deg, off, N);
    fill_csr<<<(E + 255) / 256, 256, 0, stream>>>(srcv, dstv, off, cur, dinv, edges, E);

    prep_w<<<64, 256, 0, stream>>>(W1, wt1, 128, 128);
    prep_w<<<64, 256, 0, stream>>>(W2, wt2, 128, 128);
    prep_w<<<64, 256, 0, stream>>>(W3, wt3, 128, 128);
    prep_w<<<16, 256, 0, stream>>>(W4, wt4, 128, 32);

    int gemm_blocks = (N + 63) / 64;
    int agg128_blocks = (N + 3) / 4;
    int agg32_blocks = (N * 32 + 255) / 256;

    // Layer 1 (A fp32)
    gemm128_f32A<<<gemm_blocks, 256, 0, stream>>>(x, wt1, hbuf, N);
    agg128<<<agg128_blocks, 256, 0, stream>>>(hbuf, off, edges, dinv, b1, gbuf, N);
    // Layer 2
    gemm128_bf16A<<<gemm_blocks, 256, 0, stream>>>(gbuf, wt2, hbuf, N);
    agg128<<<agg128_blocks, 256, 0, stream>>>(hbuf, off, edges, dinv, b2, gbuf, N);
    // Layer 3
    gemm128_bf16A<<<gemm_blocks, 256, 0, stream>>>(gbuf, wt3, hbuf, N);
    agg128<<<agg128_blocks, 256, 0, stream>>>(hbuf, off, edges, dinv, b3, gbuf, N);
    // Layer 4: GEMM to 32 cols, then agg + log_softmax
    gemm32_bf16A<<<gemm_blocks, 256, 0, stream>>>(gbuf, wt4, hbuf, N);
    agg32_lsm<<<agg32_blocks, 256, 0, stream>>>(hbuf, off, edges, dinv, b4, out, N);
}

// Round 4
// 931.352 us; speedup vs baseline: 1.9966x; 1.1511x over previous
//
#include <hip/hip_runtime.h>
#include <hip/hip_bf16.h>
#include <math.h>

#define NNODES 100000

typedef __hip_bfloat16 bf16;
typedef __attribute__((ext_vector_type(8))) short short8;   // bf16x8 MFMA A/B frag (4 VGPRs)
typedef __attribute__((ext_vector_type(4))) float f32x4;    // MFMA C/D frag

__device__ inline unsigned pack_bf16x2(float a, float b) {
    __hip_bfloat162 p;
    p.x = __float2bfloat16(a);
    p.y = __float2bfloat16(b);
    return *(unsigned*)&p;
}

__device__ inline float2 unpack_bf16x2(unsigned u) {
    __hip_bfloat162 p = *(__hip_bfloat162*)&u;
    return make_float2(__bfloat162float(p.x), __bfloat162float(p.y));
}

// ---------------- degree / norm ----------------
__global__ void deg_kernel(const int* __restrict__ dst, int* __restrict__ deg, int E) {
    int e = blockIdx.x * blockDim.x + threadIdx.x;
    if (e < E) atomicAdd(&deg[dst[e]], 1);
}

__global__ void dinv_kernel(const int* __restrict__ deg, float* __restrict__ dinv, int n) {
    int i = blockIdx.x * blockDim.x + threadIdx.x;
    if (i < n) dinv[i] = 1.0f / sqrtf((float)(deg[i] + 1));   // +1: self-loop
}

// ---------------- 3-phase device-wide exclusive scan over deg[0..n) ----------------
// phase 1: per-block (1024 elems) sums
__global__ __launch_bounds__(1024) void scan_phase1(const int* __restrict__ deg,
                                                    int* __restrict__ bsum, int n) {
    int i = blockIdx.x * 1024 + threadIdx.x;
    int v = (i < n) ? deg[i] : 0;
#pragma unroll
    for (int d = 32; d; d >>= 1) v += __shfl_down(v, d, 64);
    __shared__ int ws[16];
    if ((threadIdx.x & 63) == 0) ws[threadIdx.x >> 6] = v;
    __syncthreads();
    if (threadIdx.x < 16) {
        int s = ws[threadIdx.x];
#pragma unroll
        for (int d = 8; d; d >>= 1) s += __shfl_down(s, d, 16);
        if (threadIdx.x == 0) bsum[blockIdx.x] = s;
    }
}

// phase 2: single block, exclusive scan of nb (<=256) block sums; total -> off[n]
__global__ __launch_bounds__(256) void scan_phase2(int* __restrict__ bsum,
                                                   int* __restrict__ off, int nb, int n) {
    int t = threadIdx.x;
    int v = (t < nb) ? bsum[t] : 0;
    int lane = t & 63, wv = t >> 6;
    int incl = v;
#pragma unroll
    for (int d = 1; d < 64; d <<= 1) {
        int x = __shfl_up(incl, d, 64);
        if (lane >= d) incl += x;
    }
    __shared__ int wsum[4];
    if (lane == 63) wsum[wv] = incl;
    __syncthreads();
    int wo = 0;
    for (int k = 0; k < wv; ++k) wo += wsum[k];
    if (t < nb) bsum[t] = wo + incl - v;      // exclusive
    if (t == 255) off[n] = wo + incl;         // grand total == E
}

// phase 3: per-block exclusive scan + block offset
__global__ __launch_bounds__(1024) void scan_phase3(const int* __restrict__ deg,
                                                    const int* __restrict__ bsum,
                                                    int* __restrict__ off, int n) {
    int i = blockIdx.x * 1024 + threadIdx.x;
    int v = (i < n) ? deg[i] : 0;
    int lane = threadIdx.x & 63, wv = threadIdx.x >> 6;
    int incl = v;
#pragma unroll
    for (int d = 1; d < 64; d <<= 1) {
        int x = __shfl_up(incl, d, 64);
        if (lane >= d) incl += x;
    }
    __shared__ int ws[16];
    if (lane == 63) ws[wv] = incl;
    __syncthreads();
    if (threadIdx.x < 16) {
        int s = ws[threadIdx.x];
#pragma unroll
        for (int d = 1; d < 16; d <<= 1) {
            int x = __shfl_up(s, d, 16);
            if (threadIdx.x >= d) s += x;
        }
        ws[threadIdx.x] = s;                  // inclusive wave sums
    }
    __syncthreads();
    int wo = (wv == 0) ? 0 : ws[wv - 1];
    if (i < n) off[i] = bsum[blockIdx.x] + wo + incl - v;
}

// ---------------- CSR fill: ONE 8B packed scatter per edge ----------------
__global__ void fill_csr(const int* __restrict__ src, const int* __restrict__ dst,
                         const int* __restrict__ off, int* __restrict__ cur,
                         const float* __restrict__ dinv,
                         int2* __restrict__ edges, int E) {
    int e = blockIdx.x * blockDim.x + threadIdx.x;
    if (e >= E) return;
    int s = src[e], d = dst[e];
    int pos = off[d] + atomicAdd(&cur[d], 1);
    float w = dinv[s] * dinv[d];
    edges[pos] = make_int2(s, __float_as_int(w));
}

// ---------------- weight prep: WT[n][k] = bf16(W[k][n]) ----------------
__global__ void prep_w(const float* __restrict__ W, bf16* __restrict__ WT, int K, int Nout) {
    int idx = blockIdx.x * blockDim.x + threadIdx.x;
    if (idx >= K * Nout) return;
    int nn = idx / K;
    int kk = idx - nn * K;
    WT[idx] = __float2bfloat16(W[kk * Nout + nn]);
}

// ---------------- MFMA GEMM, A fp32 [n,128] x WT bf16 [128][128] -> bf16 ----------------
__global__ __launch_bounds__(256) void gemm128_f32A(const float* __restrict__ A,
                                                    const bf16* __restrict__ WT,
                                                    bf16* __restrict__ C, int n) {
    int wave = threadIdx.x >> 6;
    int lane = threadIdx.x & 63;
    int m = lane & 15;
    int q = lane >> 4;
    int row_base = blockIdx.x * 64 + wave * 16;
    int arow = min(row_base + m, n - 1);

    f32x4 acc[8];
#pragma unroll
    for (int c = 0; c < 8; ++c) acc[c] = (f32x4)(0.f);

#pragma unroll
    for (int kt = 0; kt < 4; ++kt) {
        const float* ap = &A[(size_t)arow * 128 + kt * 32 + q * 8];
        float4 f0 = *(const float4*)ap;
        float4 f1 = *(const float4*)(ap + 4);
        union { uint4 u; short8 s; } cv;
        cv.u.x = pack_bf16x2(f0.x, f0.y);
        cv.u.y = pack_bf16x2(f0.z, f0.w);
        cv.u.z = pack_bf16x2(f1.x, f1.y);
        cv.u.w = pack_bf16x2(f1.z, f1.w);
        short8 af = cv.s;
#pragma unroll
        for (int c = 0; c < 8; ++c) {
            short8 bf = *(const short8*)&WT[(size_t)(c * 16 + m) * 128 + kt * 32 + q * 8];
            acc[c] = __builtin_amdgcn_mfma_f32_16x16x32_bf16(af, bf, acc[c], 0, 0, 0);
        }
    }
#pragma unroll
    for (int c = 0; c < 8; ++c) {
#pragma unroll
        for (int r = 0; r < 4; ++r) {
            int row = row_base + q * 4 + r;
            if (row < n) C[(size_t)row * 128 + c * 16 + m] = __float2bfloat16(acc[c][r]);
        }
    }
}

// ---------------- MFMA GEMM, A bf16 [n,128] x WT bf16 [128][128] -> bf16 ----------------
__global__ __launch_bounds__(256) void gemm128_bf16A(const bf16* __restrict__ A,
                                                     const bf16* __restrict__ WT,
                                                     bf16* __restrict__ C, int n) {
    int wave = threadIdx.x >> 6;
    int lane = threadIdx.x & 63;
    int m = lane & 15;
    int q = lane >> 4;
    int row_base = blockIdx.x * 64 + wave * 16;
    int arow = min(row_base + m, n - 1);

    f32x4 acc[8];
#pragma unroll
    for (int c = 0; c < 8; ++c) acc[c] = (f32x4)(0.f);

#pragma unroll
    for (int kt = 0; kt < 4; ++kt) {
        short8 af = *(const short8*)&A[(size_t)arow * 128 + kt * 32 + q * 8];
#pragma unroll
        for (int c = 0; c < 8; ++c) {
            short8 bf = *(const short8*)&WT[(size_t)(c * 16 + m) * 128 + kt * 32 + q * 8];
            acc[c] = __builtin_amdgcn_mfma_f32_16x16x32_bf16(af, bf, acc[c], 0, 0, 0);
        }
    }
#pragma unroll
    for (int c = 0; c < 8; ++c) {
#pragma unroll
        for (int r = 0; r < 4; ++r) {
            int row = row_base + q * 4 + r;
            if (row < n) C[(size_t)row * 128 + c * 16 + m] = __float2bfloat16(acc[c][r]);
        }
    }
}

// ---------------- MFMA GEMM, A bf16 [n,128] x WT4 bf16 [32][128] -> bf16 [n,32] ----------------
__global__ __launch_bounds__(256) void gemm32_bf16A(const bf16* __restrict__ A,
                                                    const bf16* __restrict__ WT,
                                                    bf16* __restrict__ C, int n) {
    int wave = threadIdx.x >> 6;
    int lane = threadIdx.x & 63;
    int m = lane & 15;
    int q = lane >> 4;
    int row_base = blockIdx.x * 64 + wave * 16;
    int arow = min(row_base + m, n - 1);

    f32x4 acc[2];
    acc[0] = (f32x4)(0.f);
    acc[1] = (f32x4)(0.f);

#pragma unroll
    for (int kt = 0; kt < 4; ++kt) {
        short8 af = *(const short8*)&A[(size_t)arow * 128 + kt * 32 + q * 8];
#pragma unroll
        for (int c = 0; c < 2; ++c) {
            short8 bf = *(const short8*)&WT[(size_t)(c * 16 + m) * 128 + kt * 32 + q * 8];
            acc[c] = __builtin_amdgcn_mfma_f32_16x16x32_bf16(af, bf, acc[c], 0, 0, 0);
        }
    }
#pragma unroll
    for (int c = 0; c < 2; ++c) {
#pragma unroll
        for (int r = 0; r < 4; ++r) {
            int row = row_base + q * 4 + r;
            if (row < n) C[(size_t)row * 32 + c * 16 + m] = __float2bfloat16(acc[c][r]);
        }
    }
}

// ---------------- aggregation, F=128 bf16 gather -> bf16 out (one wave/node) ----------------
__global__ __launch_bounds__(256) void agg128(const bf16* __restrict__ h,
                                              const int* __restrict__ off,
                                              const int2* __restrict__ edges,
                                              const float* __restrict__ dinv,
                                              const float* __restrict__ bias,
                                              bf16* __restrict__ out, int n) {
    int wid = (blockIdx.x * blockDim.x + threadIdx.x) >> 6;
    if (wid >= n) return;
    int lane = threadIdx.x & 63;
    const unsigned* h32 = (const unsigned*)h;     // row = 64 dwords (128 bf16)
    float dl = dinv[wid];
    float sl = dl * dl;
    float2 f = unpack_bf16x2(h32[(size_t)wid * 64 + lane]);   // self-loop
    float a0 = f.x * sl, a1 = f.y * sl;
    int i0 = off[wid], i1 = off[wid + 1];
    int i = i0;
    for (; i + 8 <= i1; i += 8) {
        int2 ee[8];
#pragma unroll
        for (int j = 0; j < 8; ++j) ee[j] = edges[i + j];
        unsigned uu[8];
#pragma unroll
        for (int j = 0; j < 8; ++j) uu[j] = h32[(size_t)ee[j].x * 64 + lane];
#pragma unroll
        for (int j = 0; j < 8; ++j) {
            float w = __int_as_float(ee[j].y);
            float2 fv = unpack_bf16x2(uu[j]);
            a0 += fv.x * w; a1 += fv.y * w;
        }
    }
    for (; i < i1; ++i) {
        int2 e = edges[i];
        float w = __int_as_float(e.y);
        float2 fv = unpack_bf16x2(h32[(size_t)e.x * 64 + lane]);
        a0 += fv.x * w; a1 += fv.y * w;
    }
    float2 bv = *(const float2*)&bias[lane * 2];
    a0 += bv.x; a1 += bv.y;
    a0 = fmaxf(a0, 0.f); a1 = fmaxf(a1, 0.f);     // ReLU (layers 1-3 only)
    ((unsigned*)out)[(size_t)wid * 64 + lane] = pack_bf16x2(a0, a1);
}

// ---------------- aggregation F=32 bf16 gather + log_softmax -> fp32 ----------------
__global__ __launch_bounds__(256) void agg32_lsm(const bf16* __restrict__ h,
                                                 const int* __restrict__ off,
                                                 const int2* __restrict__ edges,
                                                 const float* __restrict__ dinv,
                                                 const float* __restrict__ bias,
                                                 float* __restrict__ out, int n) {
    int idx = blockIdx.x * blockDim.x + threadIdx.x;
    int node = idx >> 5;
    if (node >= n) return;
    int lane = idx & 31;
    const unsigned short* hu = (const unsigned short*)h;
    float dl = dinv[node];
    float a = __bfloat162float(h[(size_t)node * 32 + lane]) * dl * dl;
    int i0 = off[node], i1 = off[node + 1];
    int i = i0;
    for (; i + 8 <= i1; i += 8) {
        int2 ee[8];
#pragma unroll
        for (int j = 0; j < 8; ++j) ee[j] = edges[i + j];
        unsigned short vv[8];
#pragma unroll
        for (int j = 0; j < 8; ++j) vv[j] = hu[(size_t)ee[j].x * 32 + lane];
#pragma unroll
        for (int j = 0; j < 8; ++j) {
            bf16 b = *(bf16*)&vv[j];
            a += __bfloat162float(b) * __int_as_float(ee[j].y);
        }
    }
    for (; i < i1; ++i) {
        int2 e = edges[i];
        a += __bfloat162float(h[(size_t)e.x * 32 + lane]) * __int_as_float(e.y);
    }
    a += bias[lane];
    float mx = a;
    for (int d = 16; d; d >>= 1) mx = fmaxf(mx, __shfl_xor(mx, d, 32));
    float e = expf(a - mx);
    float ssum = e;
    for (int d = 16; d; d >>= 1) ssum += __shfl_xor(ssum, d, 32);
    out[(size_t)node * 32 + lane] = a - mx - logf(ssum);
}

extern "C" void kernel_launch(void* const* d_in, const int* in_sizes, int n_in,
                              void* d_out, int out_size, void* d_ws, size_t ws_size,
                              hipStream_t stream) {
    const float* x  = (const float*)d_in[0];
    const int*   ei = (const int*)d_in[1];
    const float* W1 = (const float*)d_in[2];
    const float* b1 = (const float*)d_in[3];
    const float* W2 = (const float*)d_in[4];
    const float* b2 = (const float*)d_in[5];
    const float* W3 = (const float*)d_in[6];
    const float* b3 = (const float*)d_in[7];
    const float* W4 = (const float*)d_in[8];
    const float* b4 = (const float*)d_in[9];
    float* out = (float*)d_out;

    const int N = NNODES;
    const int E = in_sizes[1] / 2;
    const int nb = (N + 1023) / 1024;      // scan blocks

    char* ws = (char*)d_ws;
    size_t o = 0;
    auto alloc = [&](size_t bytes) -> void* {
        void* p = ws + o;
        o += (bytes + 255) & ~(size_t)255;
        return p;
    };
    int*   deg   = (int*)alloc((size_t)N * 4);
    int*   cur   = (int*)alloc((size_t)N * 4);
    int*   off   = (int*)alloc((size_t)(N + 1) * 4);
    int*   bsum  = (int*)alloc((size_t)256 * 4);
    float* dinv  = (float*)alloc((size_t)N * 4);
    int2*  edges = (int2*)alloc((size_t)E * 8);
    bf16*  wt1   = (bf16*)alloc((size_t)128 * 128 * 2);
    bf16*  wt2   = (bf16*)alloc((size_t)128 * 128 * 2);
    bf16*  wt3   = (bf16*)alloc((size_t)128 * 128 * 2);
    bf16*  wt4   = (bf16*)alloc((size_t)32 * 128 * 2);
    bf16*  hbuf  = (bf16*)alloc((size_t)N * 128 * 2);
    bf16*  gbuf  = (bf16*)alloc((size_t)N * 128 * 2);

    const int* srcv = ei;
    const int* dstv = ei + E;

    hipMemsetAsync(deg, 0, (size_t)N * 4, stream);
    hipMemsetAsync(cur, 0, (size_t)N * 4, stream);

    deg_kernel<<<(E + 255) / 256, 256, 0, stream>>>(dstv, deg, E);
    dinv_kernel<<<(N + 255) / 256, 256, 0, stream>>>(deg, dinv, N);
    scan_phase1<<<nb, 1024, 0, stream>>>(deg, bsum, N);
    scan_phase2<<<1, 256, 0, stream>>>(bsum, off, nb, N);
    scan_phase3<<<nb, 1024, 0, stream>>>(deg, bsum, off, N);
    fill_csr<<<(E + 255) / 256, 256, 0, stream>>>(srcv, dstv, off, cur, dinv, edges, E);

    prep_w<<<64, 256, 0, stream>>>(W1, wt1, 128, 128);
    prep_w<<<64, 256, 0, stream>>>(W2, wt2, 128, 128);
    prep_w<<<64, 256, 0, stream>>>(W3, wt3, 128, 128);
    prep_w<<<16, 256, 0, stream>>>(W4, wt4, 128, 32);

    int gemm_blocks = (N + 63) / 64;
    int agg128_blocks = (N + 3) / 4;
    int agg32_blocks = (N * 32 + 255) / 256;

    // Layer 1 (A fp32)
    gemm128_f32A<<<gemm_blocks, 256, 0, stream>>>(x, wt1, hbuf, N);
    agg128<<<agg128_blocks, 256, 0, stream>>>(hbuf, off, edges, dinv, b1, gbuf, N);
    // Layer 2
    gemm128_bf16A<<<gemm_blocks, 256, 0, stream>>>(gbuf, wt2, hbuf, N);
    agg128<<<agg128_blocks, 256, 0, stream>>>(hbuf, off, edges, dinv, b2, gbuf, N);
    // Layer 3
    gemm128_bf16A<<<gemm_blocks, 256, 0, stream>>>(gbuf, wt3, hbuf, N);
    agg128<<<agg128_blocks, 256, 0, stream>>>(hbuf, off, edges, dinv, b3, gbuf, N);
    // Layer 4: GEMM to 32 cols, then agg + log_softmax
    gemm32_bf16A<<<gemm_blocks, 256, 0, stream>>>(gbuf, wt4, hbuf, N);
    agg32_lsm<<<agg32_blocks, 256, 0, stream>>>(hbuf, off, edges, dinv, b4, out, N);
}

// Round 5
// 733.667 us; speedup vs baseline: 2.5346x; 1.2694x over previous
//
#include <hip/hip_runtime.h>
#include <hip/hip_bf16.h>
#include <math.h>

#define NNODES 100000
#define NBMAX 512          // bucket arrays sized to 512; actual nb = ceil(N/256) = 391
#define CH 8192            // edges per partition block

typedef __hip_bfloat16 bf16;
typedef __attribute__((ext_vector_type(8))) short short8;   // bf16x8 MFMA A/B frag
typedef __attribute__((ext_vector_type(4))) float f32x4;    // MFMA C/D frag

__device__ inline unsigned pack_bf16x2(float a, float b) {
    __hip_bfloat162 p;
    p.x = __float2bfloat16(a);
    p.y = __float2bfloat16(b);
    return *(unsigned*)&p;
}

__device__ inline float2 unpack_bf16x2(unsigned u) {
    __hip_bfloat162 p = *(__hip_bfloat162*)&u;
    return make_float2(__bfloat162float(p.x), __bfloat162float(p.y));
}

// ---------------- phase A: bucket histogram (bucket = dst >> 8) ----------------
__global__ __launch_bounds__(256) void bucket_hist(const int* __restrict__ dst,
                                                   int* __restrict__ bcount, int E, int nb) {
    __shared__ int hist[NBMAX];
    int t = threadIdx.x;
    for (int i = t; i < NBMAX; i += 256) hist[i] = 0;
    __syncthreads();
    int e0 = blockIdx.x * CH;
#pragma unroll
    for (int k = 0; k < 32; ++k) {
        int e = e0 + t + k * 256;
        if (e < E) atomicAdd(&hist[dst[e] >> 8], 1);
    }
    __syncthreads();
    for (int i = t; i < nb; i += 256)
        if (hist[i]) atomicAdd(&bcount[i], hist[i]);
}

// ---------------- phase B: scan bucket counts (1 block, 512 threads) ----------------
__global__ __launch_bounds__(512) void bucket_scan(const int* __restrict__ bcount,
                                                   int* __restrict__ boff,
                                                   int* __restrict__ bcursor,
                                                   int* __restrict__ off, int nb, int n) {
    __shared__ int wsum[8];
    int t = threadIdx.x;
    int v = (t < nb) ? bcount[t] : 0;
    int lane = t & 63, wv = t >> 6;
    int incl = v;
#pragma unroll
    for (int d = 1; d < 64; d <<= 1) {
        int x = __shfl_up(incl, d, 64);
        if (lane >= d) incl += x;
    }
    if (lane == 63) wsum[wv] = incl;
    __syncthreads();
    int wo = 0;
    for (int k = 0; k < wv; ++k) wo += wsum[k];
    int excl = wo + incl - v;
    if (t <= nb) {
        boff[t] = excl;
        if (t < nb) bcursor[t] = excl;
    }
    if (t == nb) off[n] = excl;      // grand total == E
}

// ---------------- phase C: partition edges into bucket-contiguous ranges ----------------
// LDS counting sort per 8192-edge chunk -> coalesced global writes.
__global__ __launch_bounds__(256) void partition(const int* __restrict__ src,
                                                 const int* __restrict__ dst,
                                                 int* __restrict__ bcursor,
                                                 int2* __restrict__ part, int E, int nb) {
    __shared__ int hist[NBMAX];
    __shared__ int lstart[NBMAX];
    __shared__ int gbase[NBMAX];
    __shared__ int cursor[NBMAX];
    __shared__ int2 sorted[CH];
    int t = threadIdx.x;
    int e0 = blockIdx.x * CH;
    for (int i = t; i < NBMAX; i += 256) hist[i] = 0;
    __syncthreads();
    int mys[32], myd[32];
#pragma unroll
    for (int k = 0; k < 32; ++k) {
        int e = e0 + t + k * 256;
        int s = 0, d = -1;
        if (e < E) { s = src[e]; d = dst[e]; }
        mys[k] = s; myd[k] = d;
        if (d >= 0) atomicAdd(&hist[d >> 8], 1);
    }
    __syncthreads();
    // exclusive scan of hist (one wave, 8 entries/lane)
    if (t < 64) {
        int base = t * 8;
        int tmp[8];
        int sum = 0;
#pragma unroll
        for (int j = 0; j < 8; ++j) { tmp[j] = hist[base + j]; sum += tmp[j]; }
        int incl = sum;
#pragma unroll
        for (int d = 1; d < 64; d <<= 1) {
            int x = __shfl_up(incl, d, 64);
            if (t >= d) incl += x;
        }
        int excl = incl - sum;
#pragma unroll
        for (int j = 0; j < 8; ++j) {
            lstart[base + j] = excl;
            cursor[base + j] = excl;
            excl += tmp[j];
        }
    }
    __syncthreads();
    // reserve global ranges (one atomic per non-empty bucket per block)
    for (int i = t; i < nb; i += 256) {
        int c = hist[i];
        gbase[i] = c ? atomicAdd(&bcursor[i], c) : 0;
    }
    __syncthreads();
    // scatter into LDS in bucket-sorted order
#pragma unroll
    for (int k = 0; k < 32; ++k) {
        int d = myd[k];
        if (d >= 0) {
            int lpos = atomicAdd(&cursor[d >> 8], 1);
            sorted[lpos] = make_int2(mys[k], d);
        }
    }
    __syncthreads();
    // coalesced write-out: consecutive LDS slots -> consecutive global slots per run
    int cnt = min(CH, E - e0);
    for (int i = t; i < cnt; i += 256) {
        int2 rec = sorted[i];
        int b = rec.y >> 8;
        part[gbase[b] + (i - lstart[b])] = rec;
    }
}

// ---------------- phase D: per-bucket node degrees -> off[], dinv[] ----------------
__global__ __launch_bounds__(256) void bucket_nodes(const int2* __restrict__ part,
                                                    const int* __restrict__ boff,
                                                    float* __restrict__ dinv,
                                                    int* __restrict__ off, int n) {
    __shared__ int ndeg[256];
    __shared__ int ws2[4];
    int b = blockIdx.x;
    int t = threadIdx.x;
    ndeg[t] = 0;
    __syncthreads();
    int r0 = boff[b], r1 = boff[b + 1];
    for (int i = r0 + t; i < r1; i += 256)
        atomicAdd(&ndeg[part[i].y & 255], 1);
    __syncthreads();
    int deg = ndeg[t];
    int node = b * 256 + t;
    int lane = t & 63, wv = t >> 6;
    int incl = deg;
#pragma unroll
    for (int d = 1; d < 64; d <<= 1) {
        int x = __shfl_up(incl, d, 64);
        if (lane >= d) incl += x;
    }
    if (lane == 63) ws2[wv] = incl;
    __syncthreads();
    int wo = 0;
    for (int k = 0; k < wv; ++k) wo += ws2[k];
    if (node < n) {
        off[node] = r0 + wo + incl - deg;
        dinv[node] = rsqrtf((float)(deg + 1));     // +1: self-loop
    }
}

// ---------------- phase E: fine CSR fill (writes stay in bucket's 64KB window) ----------
__global__ __launch_bounds__(256) void fine_fill(const int2* __restrict__ part,
                                                 const int* __restrict__ boff,
                                                 const int* __restrict__ off,
                                                 const float* __restrict__ dinv,
                                                 int2* __restrict__ edges, int n) {
    __shared__ int cur[256];
    __shared__ int offl[256];
    __shared__ float dl[256];
    int b = blockIdx.x;
    int t = threadIdx.x;
    int node = b * 256 + t;
    cur[t] = 0;
    offl[t] = (node < n) ? off[node] : 0;
    dl[t] = (node < n) ? dinv[node] : 0.f;
    __syncthreads();
    int r0 = boff[b], r1 = boff[b + 1];
    for (int i = r0 + t; i < r1; i += 256) {
        int2 rec = part[i];
        int dloc = rec.y & 255;
        int s = rec.x;
        float w = dinv[s] * dl[dloc];
        int lpos = atomicAdd(&cur[dloc], 1);
        edges[offl[dloc] + lpos] = make_int2(s, __float_as_int(w));
    }
}

// ---------------- weight prep: WT[n][k] = bf16(W[k][n]) ----------------
__global__ void prep_w(const float* __restrict__ W, bf16* __restrict__ WT, int K, int Nout) {
    int idx = blockIdx.x * blockDim.x + threadIdx.x;
    if (idx >= K * Nout) return;
    int nn = idx / K;
    int kk = idx - nn * K;
    WT[idx] = __float2bfloat16(W[kk * Nout + nn]);
}

// ---------------- MFMA GEMM, A fp32 [n,128] x WT bf16 [128][128] -> bf16 ----------------
__global__ __launch_bounds__(256) void gemm128_f32A(const float* __restrict__ A,
                                                    const bf16* __restrict__ WT,
                                                    bf16* __restrict__ C, int n) {
    int wave = threadIdx.x >> 6;
    int lane = threadIdx.x & 63;
    int m = lane & 15;
    int q = lane >> 4;
    int row_base = blockIdx.x * 64 + wave * 16;
    int arow = min(row_base + m, n - 1);

    f32x4 acc[8];
#pragma unroll
    for (int c = 0; c < 8; ++c) acc[c] = (f32x4)(0.f);

#pragma unroll
    for (int kt = 0; kt < 4; ++kt) {
        const float* ap = &A[(size_t)arow * 128 + kt * 32 + q * 8];
        float4 f0 = *(const float4*)ap;
        float4 f1 = *(const float4*)(ap + 4);
        union { uint4 u; short8 s; } cv;
        cv.u.x = pack_bf16x2(f0.x, f0.y);
        cv.u.y = pack_bf16x2(f0.z, f0.w);
        cv.u.z = pack_bf16x2(f1.x, f1.y);
        cv.u.w = pack_bf16x2(f1.z, f1.w);
        short8 af = cv.s;
#pragma unroll
        for (int c = 0; c < 8; ++c) {
            short8 bf = *(const short8*)&WT[(size_t)(c * 16 + m) * 128 + kt * 32 + q * 8];
            acc[c] = __builtin_amdgcn_mfma_f32_16x16x32_bf16(af, bf, acc[c], 0, 0, 0);
        }
    }
#pragma unroll
    for (int c = 0; c < 8; ++c) {
#pragma unroll
        for (int r = 0; r < 4; ++r) {
            int row = row_base + q * 4 + r;
            if (row < n) C[(size_t)row * 128 + c * 16 + m] = __float2bfloat16(acc[c][r]);
        }
    }
}

// ---------------- MFMA GEMM, A bf16 [n,128] x WT bf16 [128][128] -> bf16 ----------------
__global__ __launch_bounds__(256) void gemm128_bf16A(const bf16* __restrict__ A,
                                                     const bf16* __restrict__ WT,
                                                     bf16* __restrict__ C, int n) {
    int wave = threadIdx.x >> 6;
    int lane = threadIdx.x & 63;
    int m = lane & 15;
    int q = lane >> 4;
    int row_base = blockIdx.x * 64 + wave * 16;
    int arow = min(row_base + m, n - 1);

    f32x4 acc[8];
#pragma unroll
    for (int c = 0; c < 8; ++c) acc[c] = (f32x4)(0.f);

#pragma unroll
    for (int kt = 0; kt < 4; ++kt) {
        short8 af = *(const short8*)&A[(size_t)arow * 128 + kt * 32 + q * 8];
#pragma unroll
        for (int c = 0; c < 8; ++c) {
            short8 bf = *(const short8*)&WT[(size_t)(c * 16 + m) * 128 + kt * 32 + q * 8];
            acc[c] = __builtin_amdgcn_mfma_f32_16x16x32_bf16(af, bf, acc[c], 0, 0, 0);
        }
    }
#pragma unroll
    for (int c = 0; c < 8; ++c) {
#pragma unroll
        for (int r = 0; r < 4; ++r) {
            int row = row_base + q * 4 + r;
            if (row < n) C[(size_t)row * 128 + c * 16 + m] = __float2bfloat16(acc[c][r]);
        }
    }
}

// ---------------- MFMA GEMM, A bf16 [n,128] x WT4 bf16 [32][128] -> bf16 [n,32] ----------------
__global__ __launch_bounds__(256) void gemm32_bf16A(const bf16* __restrict__ A,
                                                    const bf16* __restrict__ WT,
                                                    bf16* __restrict__ C, int n) {
    int wave = threadIdx.x >> 6;
    int lane = threadIdx.x & 63;
    int m = lane & 15;
    int q = lane >> 4;
    int row_base = blockIdx.x * 64 + wave * 16;
    int arow = min(row_base + m, n - 1);

    f32x4 acc[2];
    acc[0] = (f32x4)(0.f);
    acc[1] = (f32x4)(0.f);

#pragma unroll
    for (int kt = 0; kt < 4; ++kt) {
        short8 af = *(const short8*)&A[(size_t)arow * 128 + kt * 32 + q * 8];
#pragma unroll
        for (int c = 0; c < 2; ++c) {
            short8 bf = *(const short8*)&WT[(size_t)(c * 16 + m) * 128 + kt * 32 + q * 8];
            acc[c] = __builtin_amdgcn_mfma_f32_16x16x32_bf16(af, bf, acc[c], 0, 0, 0);
        }
    }
#pragma unroll
    for (int c = 0; c < 2; ++c) {
#pragma unroll
        for (int r = 0; r < 4; ++r) {
            int row = row_base + q * 4 + r;
            if (row < n) C[(size_t)row * 32 + c * 16 + m] = __float2bfloat16(acc[c][r]);
        }
    }
}

// ---------------- aggregation, F=128 bf16 gather -> bf16 out (one wave/node) ----------------
__global__ __launch_bounds__(256) void agg128(const bf16* __restrict__ h,
                                              const int* __restrict__ off,
                                              const int2* __restrict__ edges,
                                              const float* __restrict__ dinv,
                                              const float* __restrict__ bias,
                                              bf16* __restrict__ out, int n) {
    int wid = (blockIdx.x * blockDim.x + threadIdx.x) >> 6;
    if (wid >= n) return;
    int lane = threadIdx.x & 63;
    const unsigned* h32 = (const unsigned*)h;     // row = 64 dwords (128 bf16)
    float dl = dinv[wid];
    float sl = dl * dl;
    float2 f = unpack_bf16x2(h32[(size_t)wid * 64 + lane]);   // self-loop
    float a0 = f.x * sl, a1 = f.y * sl;
    int i0 = off[wid], i1 = off[wid + 1];
    int i = i0;
    for (; i + 8 <= i1; i += 8) {
        int2 ee[8];
#pragma unroll
        for (int j = 0; j < 8; ++j) ee[j] = edges[i + j];
        unsigned uu[8];
#pragma unroll
        for (int j = 0; j < 8; ++j) uu[j] = h32[(size_t)ee[j].x * 64 + lane];
#pragma unroll
        for (int j = 0; j < 8; ++j) {
            float w = __int_as_float(ee[j].y);
            float2 fv = unpack_bf16x2(uu[j]);
            a0 += fv.x * w; a1 += fv.y * w;
        }
    }
    for (; i < i1; ++i) {
        int2 e = edges[i];
        float w = __int_as_float(e.y);
        float2 fv = unpack_bf16x2(h32[(size_t)e.x * 64 + lane]);
        a0 += fv.x * w; a1 += fv.y * w;
    }
    float2 bv = *(const float2*)&bias[lane * 2];
    a0 += bv.x; a1 += bv.y;
    a0 = fmaxf(a0, 0.f); a1 = fmaxf(a1, 0.f);     // ReLU (layers 1-3 only)
    ((unsigned*)out)[(size_t)wid * 64 + lane] = pack_bf16x2(a0, a1);
}

// ---------------- aggregation F=32 bf16 gather + log_softmax -> fp32 ----------------
__global__ __launch_bounds__(256) void agg32_lsm(const bf16* __restrict__ h,
                                                 const int* __restrict__ off,
                                                 const int2* __restrict__ edges,
                                                 const float* __restrict__ dinv,
                                                 const float* __restrict__ bias,
                                                 float* __restrict__ out, int n) {
    int idx = blockIdx.x * blockDim.x + threadIdx.x;
    int node = idx >> 5;
    if (node >= n) return;
    int lane = idx & 31;
    const unsigned short* hu = (const unsigned short*)h;
    float dl = dinv[node];
    float a = __bfloat162float(h[(size_t)node * 32 + lane]) * dl * dl;
    int i0 = off[node], i1 = off[node + 1];
    int i = i0;
    for (; i + 8 <= i1; i += 8) {
        int2 ee[8];
#pragma unroll
        for (int j = 0; j < 8; ++j) ee[j] = edges[i + j];
        unsigned short vv[8];
#pragma unroll
        for (int j = 0; j < 8; ++j) vv[j] = hu[(size_t)ee[j].x * 32 + lane];
#pragma unroll
        for (int j = 0; j < 8; ++j) {
            bf16 b = *(bf16*)&vv[j];
            a += __bfloat162float(b) * __int_as_float(ee[j].y);
        }
    }
    for (; i < i1; ++i) {
        int2 e = edges[i];
        a += __bfloat162float(h[(size_t)e.x * 32 + lane]) * __int_as_float(e.y);
    }
    a += bias[lane];
    float mx = a;
    for (int d = 16; d; d >>= 1) mx = fmaxf(mx, __shfl_xor(mx, d, 32));
    float e = expf(a - mx);
    float ssum = e;
    for (int d = 16; d; d >>= 1) ssum += __shfl_xor(ssum, d, 32);
    out[(size_t)node * 32 + lane] = a - mx - logf(ssum);
}

extern "C" void kernel_launch(void* const* d_in, const int* in_sizes, int n_in,
                              void* d_out, int out_size, void* d_ws, size_t ws_size,
                              hipStream_t stream) {
    const float* x  = (const float*)d_in[0];
    const int*   ei = (const int*)d_in[1];
    const float* W1 = (const float*)d_in[2];
    const float* b1 = (const float*)d_in[3];
    const float* W2 = (const float*)d_in[4];
    const float* b2 = (const float*)d_in[5];
    const float* W3 = (const float*)d_in[6];
    const float* b3 = (const float*)d_in[7];
    const float* W4 = (const float*)d_in[8];
    const float* b4 = (const float*)d_in[9];
    float* out = (float*)d_out;

    const int N = NNODES;
    const int E = in_sizes[1] / 2;
    const int nb = (N + 255) / 256;           // 391 buckets

    char* ws = (char*)d_ws;
    size_t o = 0;
    auto alloc = [&](size_t bytes) -> void* {
        void* p = ws + o;
        o += (bytes + 255) & ~(size_t)255;
        return p;
    };
    int*   bcount  = (int*)alloc((size_t)NBMAX * 4);
    int*   boff    = (int*)alloc((size_t)(NBMAX + 1) * 4);
    int*   bcursor = (int*)alloc((size_t)NBMAX * 4);
    int*   off     = (int*)alloc((size_t)(N + 1) * 4);
    float* dinv    = (float*)alloc((size_t)N * 4);
    int2*  part    = (int2*)alloc((size_t)E * 8);      // aliased as gbuf after build
    int2*  edges   = (int2*)alloc((size_t)E * 8);
    bf16*  wt1     = (bf16*)alloc((size_t)128 * 128 * 2);
    bf16*  wt2     = (bf16*)alloc((size_t)128 * 128 * 2);
    bf16*  wt3     = (bf16*)alloc((size_t)128 * 128 * 2);
    bf16*  wt4     = (bf16*)alloc((size_t)32 * 128 * 2);
    bf16*  hbuf    = (bf16*)alloc((size_t)N * 128 * 2);
    bf16*  gbuf    = (bf16*)part;              // part dead after fine_fill; N*256B == E*8B

    const int* srcv = ei;
    const int* dstv = ei + E;

    hipMemsetAsync(bcount, 0, (size_t)NBMAX * 4, stream);

    int pblocks = (E + CH - 1) / CH;
    bucket_hist<<<pblocks, 256, 0, stream>>>(dstv, bcount, E, nb);
    bucket_scan<<<1, 512, 0, stream>>>(bcount, boff, bcursor, off, nb, N);
    partition<<<pblocks, 256, 0, stream>>>(srcv, dstv, bcursor, part, E, nb);
    bucket_nodes<<<nb, 256, 0, stream>>>(part, boff, dinv, off, N);
    fine_fill<<<nb, 256, 0, stream>>>(part, boff, off, dinv, edges, N);

    prep_w<<<64, 256, 0, stream>>>(W1, wt1, 128, 128);
    prep_w<<<64, 256, 0, stream>>>(W2, wt2, 128, 128);
    prep_w<<<64, 256, 0, stream>>>(W3, wt3, 128, 128);
    prep_w<<<16, 256, 0, stream>>>(W4, wt4, 128, 32);

    int gemm_blocks = (N + 63) / 64;
    int agg128_blocks = (N + 3) / 4;
    int agg32_blocks = (N * 32 + 255) / 256;

    // Layer 1 (A fp32)
    gemm128_f32A<<<gemm_blocks, 256, 0, stream>>>(x, wt1, hbuf, N);
    agg128<<<agg128_blocks, 256, 0, stream>>>(hbuf, off, edges, dinv, b1, gbuf, N);
    // Layer 2
    gemm128_bf16A<<<gemm_blocks, 256, 0, stream>>>(gbuf, wt2, hbuf, N);
    agg128<<<agg128_blocks, 256, 0, stream>>>(hbuf, off, edges, dinv, b2, gbuf, N);
    // Layer 3
    gemm128_bf16A<<<gemm_blocks, 256, 0, stream>>>(gbuf, wt3, hbuf, N);
    agg128<<<agg128_blocks, 256, 0, stream>>>(hbuf, off, edges, dinv, b3, gbuf, N);
    // Layer 4: GEMM to 32 cols, then agg + log_softmax
    gemm32_bf16A<<<gemm_blocks, 256, 0, stream>>>(gbuf, wt4, hbuf, N);
    agg32_lsm<<<agg32_blocks, 256, 0, stream>>>(hbuf, off, edges, dinv, b4, out, N);
}